// Round 21
// baseline (131.296 us; speedup 1.0000x reference)
//
#include <hip/hip_runtime.h>
#include <hip/hip_bf16.h>

// PosteriorRotationN: B=8,T=120,N=24,D=48,C=1128,DE=256
// kv is NEVER materialized:  sp[t,c] = XW[t,:]·ctx[c,:] + spb[t],  XW = x·Wkv (bf16)
// k0 : per-bn XW [128][256] bf16 (MFMA, R13-verified phase-0) + spb[t] = x·bkv
// k2': TT=30 (4 tiles/bn, XCD-grouped so a bn's tiles share L2 for the ctx slice);
//      phase A: B-frags straight from f32 ctx (pack8), A-frags = XW rows (K=256,
//      16 MFMA + 8 pack8 / iter, 2 t-groups share each B-frag) -> g bf16 -> sG;
//      phase B: R18-verbatim gather dot. ctx (222 MB) read from HBM exactly once.

constexpr int Bc = 8, Tc = 120, Nc = 24, Dc = 48, Cc = 1128, DEc = 256;
constexpr int BNc = Bc * Nc;        // 192

using short8 = __attribute__((ext_vector_type(8))) short;
using f32x4  = __attribute__((ext_vector_type(4))) float;

__device__ __forceinline__ ushort f2b(float f) {
    union { float f; unsigned u; } v; v.f = f;
    unsigned r = (v.u + 0x7fffu + ((v.u >> 16) & 1u)) >> 16;
    return (ushort)r;
}
__device__ __forceinline__ float b2f(ushort u) {
    union { unsigned q; float f; } cv; cv.q = ((unsigned)u) << 16; return cv.f;
}
__device__ __forceinline__ short bcast(float f) {
    return (short)__bfloat16_as_ushort(__float2bfloat16(f));
}
__device__ __forceinline__ short8 pack8(const float4& a, const float4& b) {
    short8 r;
    r[0] = bcast(a.x); r[1] = bcast(a.y); r[2] = bcast(a.z); r[3] = bcast(a.w);
    r[4] = bcast(b.x); r[5] = bcast(b.y); r[6] = bcast(b.z); r[7] = bcast(b.w);
    return r;
}

// ---------------- K0: XW = x·Wkv (bf16) + spb = x·bkv, per bn ----------------
constexpr int WTs = 64;    // sWT stride: WkvT [e][d], d-pad 48..63 = 0
constexpr int XBs = 72;    // sXb stride: x bf16, d-pad 48..63 = 0, t-pad 120..127 = row 119
__global__ __launch_bounds__(256) void k0_xw(const float* __restrict__ x,
                                             const float* __restrict__ Wkv,
                                             const float* __restrict__ bkv,
                                             ushort* __restrict__ xw,
                                             float* __restrict__ spb) {
    __shared__ ushort sWT[256 * WTs];   // 32768 B
    __shared__ ushort sXb[128 * XBs];   // 18432 B
    const int bn = blockIdx.x, b = bn / Nc, n = bn % Nc;
    const int tid = threadIdx.x, wave = tid >> 6, lane = tid & 63;
    const int tr = lane & 15, kg = lane >> 4;
    const float* xb = x + ((size_t)b * Tc * Nc + n) * Dc;

    for (int l = tid; l < (256 * WTs) / 8; l += 256)
        *reinterpret_cast<short8*>(&sWT[l * 8]) = (short8){0, 0, 0, 0, 0, 0, 0, 0};
    for (int l = tid; l < (128 * XBs) / 8; l += 256)
        *reinterpret_cast<short8*>(&sXb[l * 8]) = (short8){0, 0, 0, 0, 0, 0, 0, 0};
    __syncthreads();
    for (int l = tid; l < Dc * DEc; l += 256) {         // WkvT [e][d] bf16
        int d = l >> 8, e = l & 255;
        sWT[e * WTs + d] = f2b(Wkv[l]);
    }
    for (int l = tid; l < 128 * 12; l += 256) {         // x rows bf16 (t clamped)
        int t = l / 12, dv = (l % 12) * 4;
        int tg = t < Tc ? t : Tc - 1;
        float4 v = *reinterpret_cast<const float4*>(xb + (size_t)tg * Nc * Dc + dv);
        *reinterpret_cast<ushort4*>(&sXb[t * XBs + dv]) =
            make_ushort4(f2b(v.x), f2b(v.y), f2b(v.z), f2b(v.w));
    }
    __syncthreads();
    if (tid < 128) {                                    // spb[t] = x[t]·bkv (f32)
        int tg = tid < Tc ? tid : Tc - 1;
        float a = 0.f;
        #pragma unroll
        for (int d = 0; d < Dc; ++d) a += xb[(size_t)tg * Nc * Dc + d] * bkv[d];
        spb[(size_t)bn * 128 + tid] = a;
    }
    // XW MFMA: wave -> m-frags {wave, wave+4}; all 16 n-frags; D: col=e (tr), row=t (kg*4+r)
    ushort* xwb = xw + (size_t)bn * (128 * 256);
    #pragma unroll
    for (int mi = 0; mi < 2; ++mi) {
        const int m = wave + mi * 4;
        short8 a0 = *reinterpret_cast<const short8*>(&sXb[(m * 16 + tr) * XBs + kg * 8]);
        short8 a1 = *reinterpret_cast<const short8*>(&sXb[(m * 16 + tr) * XBs + 32 + kg * 8]);
        #pragma unroll
        for (int nf = 0; nf < 16; ++nf) {
            short8 b0 = *reinterpret_cast<const short8*>(&sWT[(nf * 16 + tr) * WTs + kg * 8]);
            short8 b1 = *reinterpret_cast<const short8*>(&sWT[(nf * 16 + tr) * WTs + 32 + kg * 8]);
            f32x4 acc = (f32x4){0.f, 0.f, 0.f, 0.f};
            acc = __builtin_amdgcn_mfma_f32_16x16x32_bf16(a0, b0, acc, 0, 0, 0);
            acc = __builtin_amdgcn_mfma_f32_16x16x32_bf16(a1, b1, acc, 0, 0, 0);
            #pragma unroll
            for (int r = 0; r < 4; ++r)
                xwb[(m * 16 + kg * 4 + r) * 256 + nf * 16 + tr] = f2b(acc[r]);
        }
    }
}

// ---------------- K2': TT=30, ctx-direct sp MFMA -> g -> gather dot ----------------
// grid 768 = 192 bn x 4 t-tiles(30). L%8 == bn%8 -> a bn's 4 tiles share an XCD/L2.
constexpr int TT4 = 30;
constexpr int SG2 = 1140;  // ushort stride (2280 B)
__global__ __launch_bounds__(256, 2) void k2_fused(const float* __restrict__ x,
                                                   const float* __restrict__ ctx,
                                                   const ushort* __restrict__ xw,
                                                   const float* __restrict__ spb,
                                                   float* __restrict__ out) {
    __shared__ ushort sG[TT4 * SG2];   // 68400 B (bf16 g)
    __shared__ float  sXf[TT4 * 52];   // 6240 B (col 48 = spb)  -> 74640 B total
    const int L = blockIdx.x;
    const int bn = (L & 7) + 8 * (L >> 5);
    const int tt = (L >> 3) & 3;
    const int b = bn / Nc, n = bn % Nc, t0 = tt * TT4;
    const int tid = threadIdx.x, wave = tid >> 6, lane = tid & 63;
    const int tr = lane & 15, kg = lane >> 4;

    // single-barrier preamble (disjoint writes)
    for (int l = tid; l < TT4 * 12; l += 256)   // zero sG pad cols 1128..1139 (d==e reads)
        sG[(l / 12) * SG2 + 1128 + (l % 12)] = 0;
    for (int l = tid; l < TT4 * 12; l += 256) { // x rows f32 (t0+t <= 119 always)
        int t = l / 12, dv = (l % 12) * 4;
        float4 v = *reinterpret_cast<const float4*>(x + (((size_t)b * Tc + t0 + t) * Nc + n) * Dc + dv);
        *reinterpret_cast<float4*>(&sXf[t * 52 + dv]) = v;
    }
    if (tid < TT4)                               // spb into col 48
        sXf[tid * 52 + 48] = spb[(size_t)bn * 128 + t0 + tid];
    // A-frags from global XW (L2-hot, 8 KB/block): two 16-t groups, K=256
    const ushort* xwb = xw + (size_t)bn * (128 * 256);
    short8 af[8], ag[8];
    #pragma unroll
    for (int ks = 0; ks < 8; ++ks) {
        af[ks] = *reinterpret_cast<const short8*>(&xwb[(size_t)(t0 + tr) * 256 + ks * 32 + kg * 8]);
        ag[ks] = *reinterpret_cast<const short8*>(&xwb[(size_t)(t0 + 16 + tr) * 256 + ks * 32 + kg * 8]);
    }
    __syncthreads();

    // phase A: 72 c-frags = 18 iters x 4 waves; B-frags direct from f32 ctx
    const float* ctxb = ctx + ((size_t)b * Cc * Nc + n) * DEc;
    for (int u = 0; u < 18; ++u) {
        int c = (wave + u * 4) * 16 + tr;
        int ce = c < Cc ? c : Cc - 1;
        const float* crow = ctxb + (size_t)ce * (Nc * DEc);
        f32x4 alo = (f32x4){0.f, 0.f, 0.f, 0.f};
        f32x4 ahi = (f32x4){0.f, 0.f, 0.f, 0.f};
        #pragma unroll
        for (int ks = 0; ks < 8; ++ks) {
            float4 q0 = *reinterpret_cast<const float4*>(crow + ks * 32 + kg * 8);
            float4 q1 = *reinterpret_cast<const float4*>(crow + ks * 32 + kg * 8 + 4);
            short8 bf = pack8(q0, q1);
            alo = __builtin_amdgcn_mfma_f32_16x16x32_bf16(af[ks], bf, alo, 0, 0, 0);
            ahi = __builtin_amdgcn_mfma_f32_16x16x32_bf16(ag[ks], bf, ahi, 0, 0, 0);
        }
        if (c < Cc) {
            #pragma unroll
            for (int r = 0; r < 4; ++r) {   // D: col=tr (=c), row=kg*4+r (=t within group)
                int tl = kg * 4 + r;
                float slo = alo[r] + sXf[tl * 52 + 48];
                float g = 0.1f - 0.2f * __builtin_amdgcn_rcpf(__expf(2.0f * slo) + 1.0f);
                sG[tl * SG2 + c] = f2b(g);
                if (tl + 16 < TT4) {
                    float shi = ahi[r] + sXf[(tl + 16) * 52 + 48];
                    float gh = 0.1f - 0.2f * __builtin_amdgcn_rcpf(__expf(2.0f * shi) + 1.0f);
                    sG[(tl + 16) * SG2 + c] = f2b(gh);
                }
            }
        }
    }
    __syncthreads();

    // phase B (R18 verbatim): thread owns up to 6 (t,e) pairs; x and g from LDS
    int ea[6], ta[6], tea[6];
    float dxa[6];
    #pragma unroll
    for (int p = 0; p < 6; ++p) {
        int idx = tid + p * 256;
        if (idx >= TT4 * 48) idx = TT4 * 48 - 1;   // clamp; result discarded at store
        ta[p] = idx / 48; ea[p] = idx % 48;
        tea[p] = ea[p] * (ea[p] - 1) / 2;
        dxa[p] = 0.f;
    }
    int td = 0;
    #pragma unroll 4
    for (int d = 0; d < 48; ++d) {
        #pragma unroll
        for (int p = 0; p < 6; ++p) {
            bool gt = d > ea[p];
            int c = gt ? (td + ea[p]) : (tea[p] + d);   // d==e -> c<=1128 (zeroed pad)
            float gv = b2f(sG[ta[p] * SG2 + c]);
            float xv = sXf[ta[p] * 52 + d];
            float m = gt ? xv : -xv;
            if (d == ea[p]) m = 0.f;
            dxa[p] = fmaf(m, gv, dxa[p]);
        }
        td += d;
    }
    #pragma unroll
    for (int p = 0; p < 6; ++p) {
        int idx = tid + p * 256;
        if (idx < TT4 * 48)
            out[(((size_t)b * Tc + t0 + ta[p]) * Nc + n) * Dc + ea[p]] = sXf[ta[p] * 52 + ea[p]] + dxa[p];
    }
}

extern "C" void kernel_launch(void* const* d_in, const int* in_sizes, int n_in,
                              void* d_out, int out_size, void* d_ws, size_t ws_size,
                              hipStream_t stream) {
    (void)in_sizes; (void)n_in; (void)out_size; (void)ws_size;
    const float* x   = (const float*)d_in[0];
    const float* ctx = (const float*)d_in[1];
    const float* Wkv = (const float*)d_in[2];
    const float* bkv = (const float*)d_in[3];
    float* out = (float*)d_out;
    ushort* xw = (ushort*)d_ws;                              // 192*128*256*2 = 12.58 MB
    float* spb = (float*)((char*)d_ws + 12582912);           // 192*128*4 = 98 KB

    k0_xw<<<dim3(BNc), dim3(256), 0, stream>>>(x, Wkv, bkv, xw, spb);
    k2_fused<<<dim3(BNc * 4), dim3(256), 0, stream>>>(x, ctx, xw, spb, out);
}

// Round 22
// 78.674 us; speedup vs baseline: 1.6689x; 1.6689x over previous
//
#include <hip/hip_runtime.h>
#include <hip/hip_bf16.h>

// PosteriorRotationN: B=8,T=120,N=24,D=48,C=1128,DE=256
// k1 : kv GEMM (bf16 MFMA, swapped operands, bn-grid) -> kvb[bn][c][48]; Wkv staged
//      directly from f32 global.
// k2 : TT=16; phase A sp MFMA (1-deep kv prefetch) -> g bf16 -> sG[t][c];
//      phase B R6-structure gather dot. 42.1 KB LDS -> 3 blk/CU. [R17/R20 config, 80.0 us]

constexpr int Bc = 8, Tc = 120, Nc = 24, Dc = 48, Cc = 1128, DEc = 256;
constexpr int BNc = Bc * Nc;        // 192
constexpr int KVP = 48;             // kv row stride (no pad; k>=48 covered by zero A-frags)

using short8 = __attribute__((ext_vector_type(8))) short;
using f32x4  = __attribute__((ext_vector_type(4))) float;

__device__ __forceinline__ ushort f2b(float f) {
    union { float f; unsigned u; } v; v.f = f;
    unsigned r = (v.u + 0x7fffu + ((v.u >> 16) & 1u)) >> 16;
    return (ushort)r;
}
__device__ __forceinline__ float b2f(ushort u) {
    union { unsigned q; float f; } cv; cv.q = ((unsigned)u) << 16; return cv.f;
}
__device__ __forceinline__ short bcast(float f) {
    return (short)__bfloat16_as_ushort(__float2bfloat16(f));
}
__device__ __forceinline__ short8 pack8(const float4& a, const float4& b) {
    short8 r;
    r[0] = bcast(a.x); r[1] = bcast(a.y); r[2] = bcast(a.z); r[3] = bcast(a.w);
    r[4] = bcast(b.x); r[5] = bcast(b.y); r[6] = bcast(b.z); r[7] = bcast(b.w);
    return r;
}

// ---------------- K1: kv GEMM, bf16 MFMA, swapped operands ----------------
constexpr int SWs = 264;  // Wkv LDS stride (bf16 elems)
__global__ __launch_bounds__(256) void k1_kv(const float* __restrict__ ctx,
                                             const float* __restrict__ Wkv,
                                             const float* __restrict__ bkv,
                                             ushort* __restrict__ kvb) {
    __shared__ ushort sW[Dc * SWs];          // 25344 B
    const int bn = blockIdx.x, c0 = blockIdx.y * 128;
    const int b = bn / Nc, n = bn % Nc;
    const int tid = threadIdx.x, wave = tid >> 6, lane = tid & 63;
    const int tr = lane & 15, kg = lane >> 4;
    const float* ctxb = ctx + ((size_t)b * Cc * Nc + n) * DEc;

    // stage Wkv f32 -> bf16 directly (12288 elems; 48 f32 per thread)
    for (int l = tid; l < Dc * 64; l += 256) {
        int d = l >> 6, e = (l & 63) << 2;
        float4 w = *reinterpret_cast<const float4*>(Wkv + d * DEc + e);
        ushort4 u;
        u.x = (ushort)bcast(w.x); u.y = (ushort)bcast(w.y);
        u.z = (ushort)bcast(w.z); u.w = (ushort)bcast(w.w);
        *reinterpret_cast<ushort4*>(&sW[d * SWs + e]) = u;
    }

    const float* crow[2];
    #pragma unroll
    for (int cn = 0; cn < 2; ++cn) {
        int c = c0 + wave * 32 + cn * 16 + tr;
        crow[cn] = ctxb + (size_t)(c < Cc ? c : Cc - 1) * (Nc * DEc);
    }

    f32x4 acc[3][2];
    #pragma unroll
    for (int mf = 0; mf < 3; ++mf)
        #pragma unroll
        for (int cn = 0; cn < 2; ++cn) acc[mf][cn] = (f32x4){0.f, 0.f, 0.f, 0.f};

    __syncthreads();

    #pragma unroll
    for (int ks = 0; ks < 8; ++ks) {
        const int e0 = ks * 32 + kg * 8;
        short8 bfrag[2];
        #pragma unroll
        for (int cn = 0; cn < 2; ++cn) {
            float4 a0 = *reinterpret_cast<const float4*>(crow[cn] + e0);
            float4 a1 = *reinterpret_cast<const float4*>(crow[cn] + e0 + 4);
            bfrag[cn] = pack8(a0, a1);
        }
        short8 afrag[3];
        #pragma unroll
        for (int mf = 0; mf < 3; ++mf)
            afrag[mf] = *reinterpret_cast<const short8*>(&sW[(mf * 16 + tr) * SWs + e0]);
        #pragma unroll
        for (int mf = 0; mf < 3; ++mf)
            #pragma unroll
            for (int cn = 0; cn < 2; ++cn)
                acc[mf][cn] = __builtin_amdgcn_mfma_f32_16x16x32_bf16(afrag[mf], bfrag[cn], acc[mf][cn], 0, 0, 0);
    }

    float4 bias[3];
    #pragma unroll
    for (int mf = 0; mf < 3; ++mf)
        bias[mf] = *reinterpret_cast<const float4*>(bkv + mf * 16 + kg * 4);
    #pragma unroll
    for (int cn = 0; cn < 2; ++cn) {
        int c = c0 + wave * 32 + cn * 16 + tr;
        if (c < Cc) {
            ushort* dst = kvb + ((size_t)bn * Cc + c) * KVP;
            #pragma unroll
            for (int mf = 0; mf < 3; ++mf) {
                ushort4 u;
                u.x = f2b(acc[mf][cn][0] + bias[mf].x);
                u.y = f2b(acc[mf][cn][1] + bias[mf].y);
                u.z = f2b(acc[mf][cn][2] + bias[mf].z);
                u.w = f2b(acc[mf][cn][3] + bias[mf].w);
                *reinterpret_cast<ushort4*>(dst + mf * 16 + kg * 4) = u;
            }
        }
    }
}

// ---------------- K2: TT=16, bf16 sG, R6 phase B, prefetched phase A, 3 blk/CU ----------------
// grid 1536 = 192 bn x 8 t-tiles(16), XCD-swizzled (L&7 == bn%8 matches k1's XCD for L2-local kvb).
constexpr int SG2 = 1140;  // ushort stride (2280 B)
__global__ __launch_bounds__(256, 3) void k2_fused(const float* __restrict__ x,
                                                   const ushort* __restrict__ kvb,
                                                   float* __restrict__ out) {
    __shared__ ushort sG[16 * SG2];    // 36480 B (bf16 g)
    __shared__ float  sXf[16 * 52];    // 3328 B
    __shared__ ushort sXb[16 * 72];    // 2304 B -> 42112 B total
    const int L = blockIdx.x;
    const int bn = (L & 7) + 8 * (L >> 6);   // bn%8 == XCD slot
    const int tt = (L >> 3) & 7;
    const int b = bn / Nc, n = bn % Nc, t0 = tt * 16;
    const int tid = threadIdx.x, wave = tid >> 6, lane = tid & 63;
    const int tr = lane & 15, kg = lane >> 4;

    // single-barrier preamble: all init writes are disjoint
    if (tid < 96) {            // zero sXb pad cols 48..71 (16 rows x 6 ushort4)
        int t = tid / 6, q = tid % 6;
        *reinterpret_cast<ushort4*>(&sXb[t * 72 + 48 + q * 4]) = make_ushort4(0, 0, 0, 0);
    }
    for (int l = tid; l < 16 * 12; l += 256)   // zero sG pad cols 1128..1139 (d==e reads)
        sG[(l / 12) * SG2 + 1128 + (l % 12)] = 0;
    if (tid < 192) {           // fill x rows: sXf f32 + sXb bf16 cols 0..47
        int t = tid / 12, dv = (tid % 12) * 4, tg = t0 + t;
        float4 v = make_float4(0.f, 0.f, 0.f, 0.f);
        if (tg < Tc) v = *reinterpret_cast<const float4*>(x + (((size_t)b * Tc + tg) * Nc + n) * Dc + dv);
        *reinterpret_cast<float4*>(&sXf[t * 52 + dv]) = v;
        *reinterpret_cast<ushort4*>(&sXb[t * 72 + dv]) = make_ushort4(f2b(v.x), f2b(v.y), f2b(v.z), f2b(v.w));
    }
    __syncthreads();
    // A-frags (t=lane&15, k contiguous-8) hoisted to regs; af1 rows for kg>=2 are ZERO
    // (sXb zero-padded past d=48) -> b1's k>=48 content is multiplied by 0 in MFMA.
    const short8 af0 = *reinterpret_cast<const short8*>(&sXb[tr * 72 + kg * 8]);
    const short8 af1 = *reinterpret_cast<const short8*>(&sXb[tr * 72 + 32 + kg * 8]);

    // phase A: 72 c-frags = 18 iters x 4 waves, 1-deep prefetch
    const ushort* kvbn = kvb + (size_t)bn * Cc * KVP;
    short8 b0, b1, p0, p1;
    {
        int c = wave * 16 + tr;
        const ushort* p = kvbn + (size_t)c * KVP + kg * 8;
        b0 = *reinterpret_cast<const short8*>(p);
        b1 = *reinterpret_cast<const short8*>(p + 32);
    }
    #pragma unroll
    for (int u = 0; u < 18; ++u) {
        if (u < 17) {
            int c = (wave + (u + 1) * 4) * 16 + tr; if (c > Cc - 1) c = Cc - 1;
            const ushort* p = kvbn + (size_t)c * KVP + kg * 8;
            p0 = *reinterpret_cast<const short8*>(p);
            p1 = *reinterpret_cast<const short8*>(p + 32);
        }
        f32x4 a = (f32x4){0.f, 0.f, 0.f, 0.f};
        a = __builtin_amdgcn_mfma_f32_16x16x32_bf16(af0, b0, a, 0, 0, 0);
        a = __builtin_amdgcn_mfma_f32_16x16x32_bf16(af1, b1, a, 0, 0, 0);
        int c = (wave + u * 4) * 16 + tr;
        if (c < Cc) {
            #pragma unroll
            for (int r = 0; r < 4; ++r) {   // D: col=tr (=c), row=kg*4+r (=t)
                float g = 0.1f - 0.2f * __builtin_amdgcn_rcpf(__expf(2.0f * a[r]) + 1.0f);
                sG[(kg * 4 + r) * SG2 + c] = f2b(g);
            }
        }
        b0 = p0; b1 = p1;
    }
    __syncthreads();

    // phase B (R6 structure): thread owns 3 (t,e) pairs; x and g from LDS, no reg arrays
    int ea[3], ta[3], tea[3];
    float dxa[3];
    #pragma unroll
    for (int p = 0; p < 3; ++p) {
        int idx = tid + p * 256;
        ta[p] = idx / 48; ea[p] = idx % 48;
        tea[p] = ea[p] * (ea[p] - 1) / 2;
        dxa[p] = 0.f;
    }
    int td = 0;
    #pragma unroll 4
    for (int d = 0; d < 48; ++d) {
        #pragma unroll
        for (int p = 0; p < 3; ++p) {
            bool gt = d > ea[p];
            int c = gt ? (td + ea[p]) : (tea[p] + d);   // d==e -> c<=1128 (zeroed pad)
            float gv = b2f(sG[ta[p] * SG2 + c]);
            float xv = sXf[ta[p] * 52 + d];
            float m = gt ? xv : -xv;
            if (d == ea[p]) m = 0.f;
            dxa[p] = fmaf(m, gv, dxa[p]);
        }
        td += d;
    }
    #pragma unroll
    for (int p = 0; p < 3; ++p) {
        int tg = t0 + ta[p];
        if (tg < Tc)
            out[(((size_t)b * Tc + tg) * Nc + n) * Dc + ea[p]] = sXf[ta[p] * 52 + ea[p]] + dxa[p];
    }
}

extern "C" void kernel_launch(void* const* d_in, const int* in_sizes, int n_in,
                              void* d_out, int out_size, void* d_ws, size_t ws_size,
                              hipStream_t stream) {
    (void)in_sizes; (void)n_in; (void)out_size; (void)ws_size;
    const float* x   = (const float*)d_in[0];
    const float* ctx = (const float*)d_in[1];
    const float* Wkv = (const float*)d_in[2];
    const float* bkv = (const float*)d_in[3];
    float* out   = (float*)d_out;
    ushort* kvb  = (ushort*)d_ws;     // 192*1128*48*2 = 20.8 MB

    k1_kv<<<dim3(BNc, 9), dim3(256), 0, stream>>>(ctx, Wkv, bkv, kvb);
    k2_fused<<<dim3(BNc * 8), dim3(256), 0, stream>>>(x, kvb, out);
}